// Round 14
// baseline (604.611 us; speedup 1.0000x reference)
//
#include <hip/hip_runtime.h>
#include <hip/hip_bf16.h>
#include <math.h>

#define NB 16384
#define NH 16
#define ND 256
#define NM 1024
#define BM 128           // rows per block
#define MB 64            // m-chunk
#define NCH (NM / MB)    // 16

typedef float f32x4 __attribute__((ext_vector_type(4)));
typedef float f32x16 __attribute__((ext_vector_type(16)));
typedef short bf16x8 __attribute__((ext_vector_type(8)));
typedef unsigned short u16;
typedef unsigned int u32;

__device__ __forceinline__ u16 f2bf(float f) {
  union { float f; unsigned u; } v; v.f = f;
  unsigned r = v.u + 0x7FFFu + ((v.u >> 16) & 1u);
  return (u16)(r >> 16);
}

// UpF[h]: granule byte off = mc*32768 + kh*1024 + m*16, kh in [0,32), m in [0,64)
//   elems e: up[h][kh*8+e][mc*64+m]   (up fp32 [H][256][1024])   [verified R8-R13]
__global__ __launch_bounds__(256) void prep_up(const float* __restrict__ src,
                                               u16* __restrict__ dst) {
  __shared__ float tile[64][65];
  const int h = blockIdx.z;
  const int m0 = blockIdx.x * 64, d0 = blockIdx.y * 64;
  const int tr = threadIdx.x >> 6, tc = threadIdx.x & 63;
  const float* s = src + (size_t)h * ND * NM;
#pragma unroll
  for (int i = 0; i < 16; ++i) {
    int r = i * 4 + tr;
    tile[r][tc] = s[(size_t)(d0 + r) * NM + m0 + tc];
  }
  __syncthreads();
  char* dh = (char*)dst + (size_t)h * NM * ND * 2;
#pragma unroll
  for (int g = 0; g < 2; ++g) {
    int gi = g * 256 + threadIdx.x;
    int kh_l = gi >> 6, m_l = gi & 63;
    bf16x8 o;
#pragma unroll
    for (int e = 0; e < 8; ++e) o[e] = (short)f2bf(tile[kh_l * 8 + e][m_l]);
    *(bf16x8*)(dh + (size_t)(m0 >> 6) * 32768 + (size_t)((d0 >> 3) + kh_l) * 1024 + m_l * 16) = o;
  }
}

// DownF[h]: granule byte off = mc*32768 + kh*4096 + d*16, kh in [0,8), d in [0,256)
//   elems e: down[h][mc*64+kh*8+e][d]   (down fp32 [H][1024][256])  [verified R8-R13]
__global__ __launch_bounds__(256) void prep_down(const float* __restrict__ src,
                                                 u16* __restrict__ dst) {
  __shared__ float tile[64][65];
  const int h = blockIdx.z;
  const int mc = blockIdx.x, d0 = blockIdx.y * 64;
  const int tr = threadIdx.x >> 6, tc = threadIdx.x & 63;
  const float* s = src + (size_t)h * NM * ND;
#pragma unroll
  for (int i = 0; i < 16; ++i) {
    int r = i * 4 + tr;
    tile[r][tc] = s[(size_t)(mc * 64 + r) * ND + d0 + tc];
  }
  __syncthreads();
  char* dh = (char*)dst + (size_t)h * NM * ND * 2;
#pragma unroll
  for (int g = 0; g < 2; ++g) {
    int gi = g * 256 + threadIdx.x;
    int kh_l = gi >> 6, d_l = gi & 63;
    bf16x8 o;
#pragma unroll
    for (int e = 0; e < 8; ++e) o[e] = (short)f2bf(tile[kh_l * 8 + e][d_l]);
    *(bf16x8*)(dh + (size_t)mc * 32768 + (size_t)kh_l * 4096 + (size_t)(d0 + d_l) * 16) = o;
  }
}

// xp[b][i] = bf16(x[b][perm[i]])
__global__ __launch_bounds__(1024) void permute_x(const float* __restrict__ x,
                                                  const int* __restrict__ perm,
                                                  u16* __restrict__ xp) {
  const int b = blockIdx.x;
  const int t = threadIdx.x;
  const float* xr = x + (size_t)b * 4096;
  int4 p = *(const int4*)(perm + t * 4);
  ushort4 o;
  o.x = f2bf(xr[p.x]); o.y = f2bf(xr[p.y]);
  o.z = f2bf(xr[p.z]); o.w = f2bf(xr[p.w]);
  *(ushort4*)(xp + (size_t)b * 4096 + t * 4) = o;
}

// out[b][j] = out[b][unperm[j]] (in place, one row per block)
__global__ __launch_bounds__(1024) void unpermute_out(float* __restrict__ out,
                                                      const int* __restrict__ unperm) {
  __shared__ float row[4096];
  const int b = blockIdx.x;
  const int t = threadIdx.x;
  float* orow = out + (size_t)b * 4096;
  *(f32x4*)(row + t * 4) = *(const f32x4*)(orow + t * 4);
  __syncthreads();
  int4 u = *(const int4*)(unperm + t * 4);
  f32x4 v;
  v.x = row[u.x]; v.y = row[u.y]; v.z = row[u.z]; v.w = row[u.w];
  *(f32x4*)(orow + t * 4) = v;
}

// SYMMETRIC 16-wave MLP = R4's proven-clean skeleton (2-barrier loop, single
// Ps, VGPR~60 no-spill, 418us) + the verified granule machinery from R8-R13:
//  - all LDS in fragment-granule order, staged LINEARLY from prep'd weights
//    (bank conflicts 37.7M -> 4.2M measured; zero per-access XOR VALU)
//  - phase B upgraded to 32x32x16 (8 MFMAs + 12 reads/wave/chunk vs R4's
//    16 MFMAs + 10 reads)
// Every 1024-thr producer/consumer variant (R10/12/13) spilled ~72-144MiB
// scratch: at 16 co-resident waves the 128-reg cap is physics, and B's
// 64-value accumulator starves the A-branch. Symmetric waves hold xr(32)
// + ca(32) + pa(8) + temps ~= 100 regs -> fits with margin.
//  phase A (swapped 16x16x32): s=w&7 strip(16r), half=w>>3 (32m);
//    per chunk: 16 av reads -> 16 MFMAs (2 indep pa chains); lane holds
//    4 consecutive m per j for x-row ll -> 2x cvt_pk b64 Ps writes.
//  phase B (32x32x16): ds2=w&3 (32r tile), q2=w>>2 (64d quarter);
//    per ks2: 1 a + 2 bv reads -> 2 MFMAs; 4 ks2 -> 12 reads / 8 MFMAs.
__global__ __launch_bounds__(1024, 4) void mlp_fused(
    const u16* __restrict__ xp,
    const u16* __restrict__ upF,
    const u16* __restrict__ downF,
    float* __restrict__ out) {
  __shared__ __align__(16) u16 Us[2][MB * ND];   // 2x32KB granules [kh32][m64]
  __shared__ __align__(16) u16 Ds[2][ND * MB];   // 2x32KB granules [kh8][d256]
  __shared__ __align__(16) u16 Ps[BM * MB];      // 16KB   granules [kh8][r128]

  const int h   = blockIdx.y;
  const int rb  = blockIdx.x;
  const int tid = threadIdx.x;
  const int w   = tid >> 6;
  const int l   = tid & 63;
  const int row0 = rb * BM;
  // phase-A mapping
  const int s    = w & 7;      // 16-row strip
  const int half = w >> 3;     // 32-m half of chunk
  const int ll   = l & 15;     // x-row within strip / frag col
  const int q    = l >> 4;     // k-quarter
  // phase-B mapping
  const int ds2  = w & 3;      // 32-row tile
  const int q2   = w >> 2;     // 64-d quarter
  const int lo   = l & 31;
  const int hi   = l >> 5;

  const char* upH = (const char*)upF + (size_t)h * NM * ND * 2;
  const char* dnH = (const char*)downF + (size_t)h * NM * ND * 2;

  // ---- X fragments: row = row0 + s*16 + ll, k = ks*32 + q*8 + e. 32 VGPR.
  bf16x8 xr[8];
  {
    const u16* px = xp + (size_t)(row0 + s * 16 + ll) * 4096 + h * ND;
#pragma unroll
    for (int ks = 0; ks < 8; ++ks)
      xr[ks] = *(const bf16x8*)(px + ks * 32 + q * 8);
  }

  // ---- linear staging (2 dwordx4/thread per buffer)
  auto stage_us = [&](int mc, int buf) {
    const char* src = upH + (size_t)mc * 32768;
#pragma unroll
    for (int j = 0; j < 2; ++j) {
      int t = j * 1024 + tid;
      __builtin_amdgcn_global_load_lds(
          (const __attribute__((address_space(1))) void*)(src + (size_t)t * 16),
          (__attribute__((address_space(3))) void*)((char*)&Us[buf][0] + (size_t)t * 16),
          16, 0, 0);
    }
  };
  auto stage_ds = [&](int mc, int buf) {
    const char* src = dnH + (size_t)mc * 32768;
#pragma unroll
    for (int j = 0; j < 2; ++j) {
      int t = j * 1024 + tid;
      __builtin_amdgcn_global_load_lds(
          (const __attribute__((address_space(1))) void*)(src + (size_t)t * 16),
          (__attribute__((address_space(3))) void*)((char*)&Ds[buf][0] + (size_t)t * 16),
          16, 0, 0);
    }
  };

  f32x16 ca[2];   // 32r x 64d per wave (2 d-tiles) -> 32 accum
#pragma unroll
  for (int dt = 0; dt < 2; ++dt)
#pragma unroll
    for (int e = 0; e < 16; ++e)
      ca[dt][e] = 0.f;

  stage_us(0, 0);
  stage_ds(0, 0);
  __syncthreads();   // chunk-0 tiles ready

  // phase-A read base: granule (ks*4+q)*64 + half*32 + j*16 + ll
  //   byte = ks*4096 + (q*64 + half*32 + ll)*16 + j*256
  const char* const ubase0 = (const char*)0 + ((size_t)q * 64 + half * 32 + ll) * 16;
  // Ps write base: value (r = s*16+ll, m = half*32 + j*16 + q*4 + e) at
  //   granule (half*4 + j*2 + (q>>1))*128 + r, byte-in-granule (q&1)*8 + e*2
  char* const psW = (char*)Ps +
                    (((size_t)(half * 4 + (q >> 1)) * 128) + s * 16 + ll) * 16 + (q & 1) * 8;
  // phase-B read bases
  const char* const abase = (const char*)Ps + ((size_t)hi * 128 + ds2 * 32 + lo) * 16;
  const size_t dbOff = (size_t)hi * 4096 + ((size_t)q2 * 64 + lo) * 16;

  for (int mc = 0; mc < NCH; ++mc) {
    const int cur = mc & 1;
    // staged loads are vmcnt-only: they stay in flight across barrier1
    // (lgkm-only) and drain at barrier2 (__syncthreads) after full cover.
    if (mc + 1 < NCH) {
      stage_us(mc + 1, cur ^ 1);
      stage_ds(mc + 1, cur ^ 1);
    }

    // ---- phase A (swapped): P^T tiles, 2 independent pa chains
    f32x4 pa[2];
#pragma unroll
    for (int j = 0; j < 2; ++j) { f32x4 z = {0.f, 0.f, 0.f, 0.f}; pa[j] = z; }
    {
      const char* ub = (const char*)&Us[cur][0] + (size_t)(ubase0 - (const char*)0);
      __builtin_amdgcn_s_setprio(1);
#pragma unroll
      for (int ks = 0; ks < 8; ++ks) {
        bf16x8 av0 = *(const bf16x8*)(ub + (size_t)ks * 4096);
        bf16x8 av1 = *(const bf16x8*)(ub + (size_t)ks * 4096 + 256);
        pa[0] = __builtin_amdgcn_mfma_f32_16x16x32_bf16(av0, xr[ks], pa[0], 0, 0, 0);
        pa[1] = __builtin_amdgcn_mfma_f32_16x16x32_bf16(av1, xr[ks], pa[1], 0, 0, 0);
      }
      __builtin_amdgcn_s_setprio(0);
    }

    // ---- gelu -> cvt_pk pack -> 2x ds_write_b64 (lane-linear, conflict-free)
#pragma unroll
    for (int j = 0; j < 2; ++j) {
      float gv[4];
#pragma unroll
      for (int e = 0; e < 4; ++e) {
        float v = pa[j][e];
        float p = __builtin_fmaf(0.1029433f, v * v, 2.3022082f);
        float ex = __builtin_amdgcn_exp2f(v * p);
        float r = __builtin_amdgcn_rcpf(ex + 1.0f);
        gv[e] = __builtin_fmaf(-v, r, v);
      }
      u32 w0, w1;
      asm("v_cvt_pk_bf16_f32 %0, %1, %2" : "=v"(w0) : "v"(gv[0]), "v"(gv[1]));
      asm("v_cvt_pk_bf16_f32 %0, %1, %2" : "=v"(w1) : "v"(gv[2]), "v"(gv[3]));
      uint2 pk; pk.x = w0; pk.y = w1;
      *(uint2*)(psW + (size_t)j * 4096) = pk;
    }

    // barrier1: Ps handoff (DS only); staged vmem loads NOT drained here
    __builtin_amdgcn_sched_barrier(0);
    asm volatile("s_waitcnt lgkmcnt(0)" ::: "memory");
    __builtin_amdgcn_s_barrier();
    __builtin_amdgcn_sched_barrier(0);

    // ---- phase B: C[32r x 64d] += Ps @ Ds[cur]  (4 a + 8 bv reads, 8 MFMAs)
    {
      const char* dbase = (const char*)&Ds[cur][0] + dbOff;
      __builtin_amdgcn_s_setprio(1);
#pragma unroll
      for (int ks2 = 0; ks2 < 4; ++ks2) {
        bf16x8 a  = *(const bf16x8*)(abase + (size_t)ks2 * 4096);
        bf16x8 b0 = *(const bf16x8*)(dbase + (size_t)ks2 * 8192);
        bf16x8 b1 = *(const bf16x8*)(dbase + (size_t)ks2 * 8192 + 512);
        ca[0] = __builtin_amdgcn_mfma_f32_32x32x16_bf16(a, b0, ca[0], 0, 0, 0);
        ca[1] = __builtin_amdgcn_mfma_f32_32x32x16_bf16(a, b1, ca[1], 0, 0, 0);
      }
      __builtin_amdgcn_s_setprio(0);
    }

    // barrier2: Ps reads done; staged tiles landed (full-chunk cover)
    __syncthreads();
  }

  // ---- epilogue: out[b][h*256+d], coalesced (32 consecutive d per lane row)
  // C-layout 32x32: col d = lo, row = (reg&3) + 8*(reg>>2) + 4*hi.
#pragma unroll
  for (int dt = 0; dt < 2; ++dt) {
    const int d = h * ND + q2 * 64 + dt * 32 + lo;
#pragma unroll
    for (int reg = 0; reg < 16; ++reg) {
      int r = ds2 * 32 + (reg & 3) + 8 * (reg >> 2) + 4 * hi;
      out[(size_t)(row0 + r) * 4096 + d] = ca[dt][reg];
    }
  }
}

extern "C" void kernel_launch(void* const* d_in, const int* in_sizes, int n_in,
                              void* d_out, int out_size, void* d_ws, size_t ws_size,
                              hipStream_t stream) {
  const float* x    = (const float*)d_in[0];
  const float* up   = (const float*)d_in[1];
  const float* down = (const float*)d_in[2];
  const int* perm   = (const int*)d_in[3];
  const int* unperm = (const int*)d_in[4];
  float* out = (float*)d_out;

  u16* upF   = (u16*)d_ws;                                   // 8 MB
  u16* downF = upF + (size_t)NH * NM * ND;                   // 8 MB
  u16* xp    = downF + (size_t)NH * NM * ND;                 // 128 MB

  // weights -> fragment-granule order (one-time, coalesced tile transposes)
  prep_up<<<dim3(NM / 64, ND / 64, NH), 256, 0, stream>>>(up, upF);
  prep_down<<<dim3(NM / 64, ND / 64, NH), 256, 0, stream>>>(down, downF);
  // xp[b][i] = bf16(x[b][perm[i]])
  permute_x<<<NB, 1024, 0, stream>>>(x, perm, xp);
  // main fused MLP: 16 symmetric waves, granule LDS, 144KB, no-spill loadout.
  mlp_fused<<<dim3(NB / BM, NH), 1024, 0, stream>>>(xp, upF, downF, out);
  // in-place feature unpermute
  unpermute_out<<<NB, 1024, 0, stream>>>(out, unperm);
}

// Round 15
// 522.973 us; speedup vs baseline: 1.1561x; 1.1561x over previous
//
#include <hip/hip_runtime.h>
#include <hip/hip_bf16.h>
#include <math.h>

#define NB 16384
#define NH 16
#define ND 256
#define NM 1024
#define BM 128           // rows per block
#define MB 64            // m-chunk
#define NCH (NM / MB)    // 16

typedef float f32x4 __attribute__((ext_vector_type(4)));
typedef float f32x16 __attribute__((ext_vector_type(16)));
typedef short bf16x8 __attribute__((ext_vector_type(8)));
typedef unsigned short u16;
typedef unsigned int u32;

__device__ __forceinline__ u16 f2bf(float f) {
  union { float f; unsigned u; } v; v.f = f;
  unsigned r = v.u + 0x7FFFu + ((v.u >> 16) & 1u);
  return (u16)(r >> 16);
}

// UpF[h]: granule byte off = mc*32768 + kh*1024 + m*16, kh in [0,32), m in [0,64)
//   elems e: up[h][kh*8+e][mc*64+m]   (up fp32 [H][256][1024])
__global__ __launch_bounds__(256) void prep_up(const float* __restrict__ src,
                                               u16* __restrict__ dst) {
  __shared__ float tile[64][65];
  const int h = blockIdx.z;
  const int m0 = blockIdx.x * 64, d0 = blockIdx.y * 64;
  const int tr = threadIdx.x >> 6, tc = threadIdx.x & 63;
  const float* s = src + (size_t)h * ND * NM;
#pragma unroll
  for (int i = 0; i < 16; ++i) {
    int r = i * 4 + tr;
    tile[r][tc] = s[(size_t)(d0 + r) * NM + m0 + tc];
  }
  __syncthreads();
  char* dh = (char*)dst + (size_t)h * NM * ND * 2;
#pragma unroll
  for (int g = 0; g < 2; ++g) {
    int gi = g * 256 + threadIdx.x;
    int kh_l = gi >> 6, m_l = gi & 63;
    bf16x8 o;
#pragma unroll
    for (int e = 0; e < 8; ++e) o[e] = (short)f2bf(tile[kh_l * 8 + e][m_l]);
    *(bf16x8*)(dh + (size_t)(m0 >> 6) * 32768 + (size_t)((d0 >> 3) + kh_l) * 1024 + m_l * 16) = o;
  }
}

// DownF[h]: granule byte off = mc*32768 + kh*4096 + d*16, kh in [0,8), d in [0,256)
//   elems e: down[h][mc*64+kh*8+e][d]   (down fp32 [H][1024][256])
__global__ __launch_bounds__(256) void prep_down(const float* __restrict__ src,
                                                 u16* __restrict__ dst) {
  __shared__ float tile[64][65];
  const int h = blockIdx.z;
  const int mc = blockIdx.x, d0 = blockIdx.y * 64;
  const int tr = threadIdx.x >> 6, tc = threadIdx.x & 63;
  const float* s = src + (size_t)h * NM * ND;
#pragma unroll
  for (int i = 0; i < 16; ++i) {
    int r = i * 4 + tr;
    tile[r][tc] = s[(size_t)(mc * 64 + r) * ND + d0 + tc];
  }
  __syncthreads();
  char* dh = (char*)dst + (size_t)h * NM * ND * 2;
#pragma unroll
  for (int g = 0; g < 2; ++g) {
    int gi = g * 256 + threadIdx.x;
    int kh_l = gi >> 6, d_l = gi & 63;
    bf16x8 o;
#pragma unroll
    for (int e = 0; e < 8; ++e) o[e] = (short)f2bf(tile[kh_l * 8 + e][d_l]);
    *(bf16x8*)(dh + (size_t)mc * 32768 + (size_t)kh_l * 4096 + (size_t)(d0 + d_l) * 16) = o;
  }
}

// xp[b][i] = bf16(x[b][perm[i]])
__global__ __launch_bounds__(1024) void permute_x(const float* __restrict__ x,
                                                  const int* __restrict__ perm,
                                                  u16* __restrict__ xp) {
  const int b = blockIdx.x;
  const int t = threadIdx.x;
  const float* xr = x + (size_t)b * 4096;
  int4 p = *(const int4*)(perm + t * 4);
  ushort4 o;
  o.x = f2bf(xr[p.x]); o.y = f2bf(xr[p.y]);
  o.z = f2bf(xr[p.z]); o.w = f2bf(xr[p.w]);
  *(ushort4*)(xp + (size_t)b * 4096 + t * 4) = o;
}

// out[b][j] = fp32(pre[b][unperm[j]]); pre is the bf16 pre-unpermute output
// that mlp_fused wrote back into the xp buffer. 384 MiB traffic vs the old
// in-place fp32 unpermute's 512 MiB.
__global__ __launch_bounds__(1024) void unpermute_cvt(const u16* __restrict__ pre,
                                                      const int* __restrict__ unperm,
                                                      float* __restrict__ out) {
  __shared__ u16 row[4096];
  const int b = blockIdx.x;
  const int t = threadIdx.x;
  const u16* prow = pre + (size_t)b * 4096;
  *(ushort4*)(row + t * 4) = *(const ushort4*)(prow + t * 4);
  __syncthreads();
  int4 u = *(const int4*)(unperm + t * 4);
  f32x4 v;
  union { u32 u; float f; } c0, c1, c2, c3;
  c0.u = (u32)row[u.x] << 16; c1.u = (u32)row[u.y] << 16;
  c2.u = (u32)row[u.z] << 16; c3.u = (u32)row[u.w] << 16;
  v.x = c0.f; v.y = c1.f; v.z = c2.f; v.w = c3.f;
  *(f32x4*)(out + (size_t)b * 4096 + t * 4) = v;
}

// 16-wave PRODUCER/CONSUMER MLP -- the best-measured main loop (R10, 404us)
// kept verbatim, with the epilogue changed to write bf16 pre-output INTO THE
// XP BUFFER (coalesced u16 stores, half the out-write bytes). Aliasing safe:
// block (rb,h) reads exactly xp[row0..row0+127][h*256..h*256+255] into regs
// at its prologue (A-waves, before loop barrier #1) and writes exactly that
// region at its epilogue (B-waves, after barrier #NCH >= #1); no other block
// touches the region. The fp32 unpermute+cvt happens in unpermute_cvt.
__global__ __launch_bounds__(1024, 4) void mlp_fused(
    u16* __restrict__ xp,
    const u16* __restrict__ upF,
    const u16* __restrict__ downF) {
  __shared__ __align__(16) u16 Us[2][MB * ND];   // 2x32KB [kh32][m64][8]
  __shared__ __align__(16) u16 Ds[2][ND * MB];   // 2x32KB [kh8][d256][8]
  __shared__ __align__(16) u16 Ps[2][BM * MB];   // 2x16KB [kh8][r128][8]

  const int h   = blockIdx.y;
  const int rb  = blockIdx.x;
  const int tid = threadIdx.x;
  const int w   = tid >> 6;
  const int l   = tid & 63;
  const int lo  = l & 31;
  const int hi  = l >> 5;
  const int row0 = rb * BM;

  const char* upH = (const char*)upF + (size_t)h * NM * ND * 2;
  const char* dnH = (const char*)downF + (size_t)h * NM * ND * 2;

  // ---- prologue: all 16 waves stage Us(0) (2 insts/thread), then barrier
  {
#pragma unroll
    for (int i = 0; i < 2; ++i) {
      int t = i * 1024 + tid;
      __builtin_amdgcn_global_load_lds(
          (const __attribute__((address_space(1))) void*)(upH + (size_t)t * 16),
          (__attribute__((address_space(3))) void*)((char*)&Us[0][0] + (size_t)t * 16),
          16, 0, 0);
    }
  }
  asm volatile("s_waitcnt vmcnt(0)" ::: "memory");
  __builtin_amdgcn_s_barrier();

  if (w < 8) {
    // ================= producer (A) =================
    const int rtA = w & 3;    // 32-row tile
    const int mt  = w >> 2;   // 32-m tile of the 64-m chunk

    // X fragments: lane = x-row (rtA*32+lo), k = ks*16 + hi*8 + e. 64 VGPR.
    bf16x8 xr[16];
    {
      const char* px = (const char*)(xp + (size_t)(row0 + rtA * 32 + lo) * 4096 + h * ND);
#pragma unroll
      for (int ks = 0; ks < 16; ++ks)
        xr[ks] = *(const bf16x8*)(px + ks * 32 + hi * 16);
    }
    char* const psW = (char*)&Ps[0][0] + (size_t)(rtA * 32 + lo) * 16 + hi * 8;

    for (int i = 0; i < NCH; ++i) {
      const int c = i & 1;
      // stage Us(i+1) -> buf c^1 (A-threads: tid in [0,512), 4 insts)
      if (i + 1 < NCH) {
        const char* src = upH + (size_t)(i + 1) * 32768;
#pragma unroll
        for (int j = 0; j < 4; ++j) {
          int t = j * 512 + tid;
          __builtin_amdgcn_global_load_lds(
              (const __attribute__((address_space(1))) void*)(src + (size_t)t * 16),
              (__attribute__((address_space(3))) void*)((char*)&Us[c ^ 1][0] + (size_t)t * 16),
              16, 0, 0);
        }
      }

      // A(i): P^T[32m x 32r] = Up-frags @ X-frags (single chain-16; 2A+2B
      // waves/SIMD keep the pipe fed)
      f32x16 pa;
#pragma unroll
      for (int e = 0; e < 16; ++e) pa[e] = 0.f;
      {
        const char* ub = (const char*)&Us[c][0] + (size_t)(mt * 32 + lo) * 16 + hi * 1024;
        __builtin_amdgcn_s_setprio(1);
#pragma unroll
        for (int ks = 0; ks < 16; ++ks) {
          bf16x8 av = *(const bf16x8*)(ub + ks * 2048);
          pa = __builtin_amdgcn_mfma_f32_32x32x16_bf16(av, xr[ks], pa, 0, 0, 0);
        }
        __builtin_amdgcn_s_setprio(0);
      }

      // gelu -> pack -> 4x ds_write_b64 into Ps[c]
      // pa[4g+e] = P[r=rtA*32+lo][m = mt*32 + g*8 + hi*4 + e]
#pragma unroll
      for (int g = 0; g < 4; ++g) {
        float gv[4];
#pragma unroll
        for (int e = 0; e < 4; ++e) {
          float v = pa[g * 4 + e];
          float p = __builtin_fmaf(0.1029433f, v * v, 2.3022082f);
          float ex = __builtin_amdgcn_exp2f(v * p);
          float r = __builtin_amdgcn_rcpf(ex + 1.0f);
          gv[e] = __builtin_fmaf(-v, r, v);
        }
        u32 w0, w1;
        asm("v_cvt_pk_bf16_f32 %0, %1, %2" : "=v"(w0) : "v"(gv[0]), "v"(gv[1]));
        asm("v_cvt_pk_bf16_f32 %0, %1, %2" : "=v"(w1) : "v"(gv[2]), "v"(gv[3]));
        uint2 pk; pk.x = w0; pk.y = w1;
        *(uint2*)(psW + (size_t)c * (BM * MB * 2) + (size_t)(mt * 4 + g) * 2048) = pk;
      }

      __builtin_amdgcn_sched_barrier(0);
      asm volatile("s_waitcnt lgkmcnt(0)" ::: "memory");   // Ps published
      asm volatile("s_waitcnt vmcnt(0)" ::: "memory");     // Us(i+1) landed
      __builtin_amdgcn_s_barrier();
      __builtin_amdgcn_sched_barrier(0);
    }
    // A-waves done (pre-out written by B-waves)
  } else {
    // ================= consumer (B) =================
    const int wb  = w - 8;
    const int rtp = wb & 1;   // 64-row half
    const int dq  = wb >> 1;  // 64-d quarter
    const int tb  = tid - 512;

    f32x16 ca[2][2];   // [rt2][dt] 32x32 tiles: 64r x 64d -> 64 VGPR
#pragma unroll
    for (int rt2 = 0; rt2 < 2; ++rt2)
#pragma unroll
      for (int dt = 0; dt < 2; ++dt)
#pragma unroll
        for (int e = 0; e < 16; ++e)
          ca[rt2][dt][e] = 0.f;

    for (int i = 0; i < NCH; ++i) {
      const int c = i & 1;
      // stage Ds(i) -> buf c (B-threads, 4 insts)
      {
        const char* src = dnH + (size_t)i * 32768;
#pragma unroll
        for (int j = 0; j < 4; ++j) {
          int t = j * 512 + tb;
          __builtin_amdgcn_global_load_lds(
              (const __attribute__((address_space(1))) void*)(src + (size_t)t * 16),
              (__attribute__((address_space(3))) void*)((char*)&Ds[c][0] + (size_t)t * 16),
              16, 0, 0);
        }
      }

      // B(i-1): C += Ps[c^1] @ Ds[c^1]
      if (i > 0) {
        const char* psb = (const char*)&Ps[c ^ 1][0];
        const char* dsb = (const char*)&Ds[c ^ 1][0];
        __builtin_amdgcn_s_setprio(1);
#pragma unroll
        for (int ks = 0; ks < 4; ++ks) {
          const size_t khp = (size_t)(ks * 2 + hi);
          bf16x8 a0 = *(const bf16x8*)(psb + khp * 2048 + (size_t)(rtp * 64 + lo) * 16);
          bf16x8 a1 = *(const bf16x8*)(psb + khp * 2048 + (size_t)(rtp * 64 + 32 + lo) * 16);
#pragma unroll
          for (int dt = 0; dt < 2; ++dt) {
            bf16x8 bv = *(const bf16x8*)(dsb + khp * 4096 + (size_t)(dq * 64 + dt * 32 + lo) * 16);
            ca[0][dt] = __builtin_amdgcn_mfma_f32_32x32x16_bf16(a0, bv, ca[0][dt], 0, 0, 0);
            ca[1][dt] = __builtin_amdgcn_mfma_f32_32x32x16_bf16(a1, bv, ca[1][dt], 0, 0, 0);
          }
        }
        __builtin_amdgcn_s_setprio(0);
      }

      __builtin_amdgcn_sched_barrier(0);
      asm volatile("s_waitcnt vmcnt(0)" ::: "memory");     // Ds(i) landed
      __builtin_amdgcn_s_barrier();
      __builtin_amdgcn_sched_barrier(0);
    }

    // final B(NCH-1): Ps[1], Ds[1]
    {
      const int c = (NCH - 1) & 1;
      const char* psb = (const char*)&Ps[c][0];
      const char* dsb = (const char*)&Ds[c][0];
      __builtin_amdgcn_s_setprio(1);
#pragma unroll
      for (int ks = 0; ks < 4; ++ks) {
        const size_t khp = (size_t)(ks * 2 + hi);
        bf16x8 a0 = *(const bf16x8*)(psb + khp * 2048 + (size_t)(rtp * 64 + lo) * 16);
        bf16x8 a1 = *(const bf16x8*)(psb + khp * 2048 + (size_t)(rtp * 64 + 32 + lo) * 16);
#pragma unroll
        for (int dt = 0; dt < 2; ++dt) {
          bf16x8 bv = *(const bf16x8*)(dsb + khp * 4096 + (size_t)(dq * 64 + dt * 32 + lo) * 16);
          ca[0][dt] = __builtin_amdgcn_mfma_f32_32x32x16_bf16(a0, bv, ca[0][dt], 0, 0, 0);
          ca[1][dt] = __builtin_amdgcn_mfma_f32_32x32x16_bf16(a1, bv, ca[1][dt], 0, 0, 0);
        }
      }
      __builtin_amdgcn_s_setprio(0);
    }

    // epilogue: bf16 pre-out into the xp buffer (coalesced u16 stores;
    // 32 consecutive d per 32-lane group). C-layout 32x32: col d = lo,
    // row = (reg&3) + 8*(reg>>2) + 4*hi.
#pragma unroll
    for (int rt2 = 0; rt2 < 2; ++rt2)
#pragma unroll
      for (int dt = 0; dt < 2; ++dt) {
        const int d = h * ND + dq * 64 + dt * 32 + lo;
#pragma unroll
        for (int reg = 0; reg < 16; ++reg) {
          int r = rtp * 64 + rt2 * 32 + (reg & 3) + 8 * (reg >> 2) + 4 * hi;
          xp[(size_t)(row0 + r) * 4096 + d] = f2bf(ca[rt2][dt][reg]);
        }
      }
  }
}

extern "C" void kernel_launch(void* const* d_in, const int* in_sizes, int n_in,
                              void* d_out, int out_size, void* d_ws, size_t ws_size,
                              hipStream_t stream) {
  const float* x    = (const float*)d_in[0];
  const float* up   = (const float*)d_in[1];
  const float* down = (const float*)d_in[2];
  const int* perm   = (const int*)d_in[3];
  const int* unperm = (const int*)d_in[4];
  float* out = (float*)d_out;

  u16* upF   = (u16*)d_ws;                                   // 8 MB
  u16* downF = upF + (size_t)NH * NM * ND;                   // 8 MB
  u16* xp    = downF + (size_t)NH * NM * ND;                 // 128 MB (xp, then pre-out)

  // weights -> fragment-granule order (one-time, coalesced tile transposes)
  prep_up<<<dim3(NM / 64, ND / 64, NH), 256, 0, stream>>>(up, upF);
  prep_down<<<dim3(NM / 64, ND / 64, NH), 256, 0, stream>>>(down, downF);
  // xp[b][i] = bf16(x[b][perm[i]])
  permute_x<<<NB, 1024, 0, stream>>>(x, perm, xp);
  // main fused MLP: 1024 thr (8 producer + 8 consumer waves), 160KB LDS.
  // Writes bf16 pre-out back into xp (aliasing-safe per block region).
  mlp_fused<<<dim3(NB / BM, NH), 1024, 0, stream>>>(xp, upF, downF);
  // unpermute + bf16->fp32 cvt into the real output
  unpermute_cvt<<<NB, 1024, 0, stream>>>(xp, unperm, out);
}